// Round 6
// baseline (806.847 us; speedup 1.0000x reference)
//
#include <hip/hip_runtime.h>

// ---------------------------------------------------------------------------
// StructuralCausalModel: 3 layers x 32 vars sequential scan, BATCH=512.
// R6: stop fighting the register allocator (R4/R5 spilled); attack the
// latency-serial chain with block-level parallelism instead: BTILE=4,
// 128 blocks -> 2 blocks/CU co-resident (LDS 70.4 KB/block), total regs/wave
// capped 128 via __launch_bounds__(512,4) and per-step (not cross-step)
// fragment loads. Garbage M-rows 4..15 of the 16-row MFMA tile are discarded
// (row-independent), so activation LDS shrinks to 4 rows, no zero-pad.
// ---------------------------------------------------------------------------

typedef __bf16 bf16x8 __attribute__((ext_vector_type(8)));
typedef float  f32x4  __attribute__((ext_vector_type(4)));

#define N_VARS 32
#define BTILE 4
#define NBLK 128

// ws element offsets (bf16 region starts at byte 4096; adjT f32 at byte 0)
#define ELOFF_PA 0
#define ELOFF_W1 65536
#define ELOFF_W2 1114112
#define ELOFF_W3 1638400
// total bf16 el = 2686976 -> ws bytes = 4096 + 5373952

__device__ __forceinline__ unsigned short f2b(float f) {
    unsigned u = __float_as_uint(f);
    u += 0x7FFFu + ((u >> 16) & 1u);
    return (unsigned short)(u >> 16);
}

// lgkm-only barrier: LDS ordering enforced, global loads stay in flight.
__device__ __forceinline__ void bar_lds() {
    asm volatile("s_waitcnt lgkmcnt(0)\n\ts_barrier" ::: "memory");
}

// erf via Abramowitz-Stegun 7.1.25, 3 terms (|err| <= 2.5e-5)
__device__ __forceinline__ float gelu_e(float x) {
    float z  = x * 0.7071067811865476f;
    float az = fabsf(z);
    float t  = __builtin_amdgcn_rcpf(1.0f + 0.47047f * az);
    float p  = t * (0.3480242f + t * (-0.0958798f + t * 0.7478556f));
    float e  = 1.0f - p * __expf(-z * z);
    float er = (z < 0.0f) ? -e : e;
    return 0.5f * x * (1.0f + er);
}

// ---------------------------------------------------------------------------
// Prep (1545 blocks x 256): [0,520) weight swizzle via LDS tile (coalesced);
// 520 adjacency; [521,1545) noise encoder NE -> d_out (16 rows/block).
// B-frag (16x16x32): lane l, elem j -> k = ks*32+(l>>4)*8+j, n = nt*16+(l&15)
// ---------------------------------------------------------------------------
__global__ void prep_all(const float* __restrict__ paW, const float* __restrict__ mW1,
                         const float* __restrict__ mW2, const float* __restrict__ mW3,
                         const float* __restrict__ edge, unsigned short* __restrict__ wsb,
                         float* __restrict__ adjT,
                         const float* __restrict__ noise, const float* __restrict__ neW,
                         const float* __restrict__ neb, float* __restrict__ outp) {
    __shared__ unsigned short tile[32 * 256];
    const int c = blockIdx.x, tid = threadIdx.x;
    if (c < 520) {
        const float* src; unsigned short* dst; int N, KS, ks;
        if (c < 8)        { src = paW;                     dst = wsb + ELOFF_PA;             N = 256; KS = 8; ks = c; }
        else if (c < 264) { int v = (c - 8) >> 3;   ks = (c - 8) & 7;
                            src = mW1 + v * 32768;         dst = wsb + ELOFF_W1 + v * 32768; N = 128; KS = 8; }
        else if (c < 392) { int v = (c - 264) >> 2; ks = (c - 264) & 3;
                            src = mW2 + v * 16384;         dst = wsb + ELOFF_W2 + v * 16384; N = 128; KS = 4; }
        else              { int v = (c - 392) >> 2; ks = (c - 392) & 3;
                            src = mW3 + v * 32768;         dst = wsb + ELOFF_W3 + v * 32768; N = 256; KS = 4; }
        const int kb = ks * 32, nsh = (N == 256) ? 8 : 7;
        for (int t = tid; t < 32 * N; t += 256) {
            int r = t >> nsh, col = t & (N - 1);
            tile[r * N + col] = f2b(src[(kb + r) * N + col]);   // coalesced in col
        }
        __syncthreads();
        const int nout = (N >> 4) * 64;
        for (int o = tid; o < nout; o += 256) {
            int nt = o >> 6, lane = o & 63;
            int n = nt * 16 + (lane & 15), k0 = (lane >> 4) << 3;
            unsigned e[8];
            #pragma unroll
            for (int j = 0; j < 8; j++) e[j] = tile[(k0 + j) * N + n];
            uint4 pk;
            pk.x = e[0] | (e[1] << 16); pk.y = e[2] | (e[3] << 16);
            pk.z = e[4] | (e[5] << 16); pk.w = e[6] | (e[7] << 16);
            *(uint4*)(dst + ((nt * KS + ks) * 64 + lane) * 8) = pk;   // coalesced
        }
    } else if (c == 520) {
        for (int t = tid; t < 1024; t += 256) {
            int v = t >> 5, ci = t & 31;
            float x = edge[t];
            float m = (v == ci) ? 0.0f : x;   // diag logit masked -> adj diag = 0.5
            adjT[ci * 32 + v] = __builtin_amdgcn_rcpf(1.0f + __expf(-2.0f * m));
        }
    } else {
        int sb = c - 521;                     // 1024 sub-blocks: 32 vars x 32 groups
        int i = sb >> 5, g = sb & 31, d = tid;
        float w[64];
        #pragma unroll
        for (int k = 0; k < 64; k++) w[k] = neW[(i * 64 + k) * 256 + d];
        float bias = neb[i * 256 + d];
        for (int bb = 0; bb < 16; bb++) {
            int b = g * 16 + bb;
            const float* nr = noise + (b * 32 + i) * 64;
            float acc = bias;
            #pragma unroll
            for (int k = 0; k < 64; k++) acc += nr[k] * w[k];
            outp[(b * 32 + i) * 256 + d] = gelu_e(acc);
        }
    }
}

#define MFMA16(a, b, c) __builtin_amdgcn_mfma_f32_16x16x32_bf16(a, b, c, 0, 0, 0)

// ---------------------------------------------------------------------------
// Main: 128 blocks x 512 threads, 2 blocks/CU (LDS 70.4 KB, <=128 regs/wave).
// Per step: [P: pc | load paf, then w1f] [A: pa | load w2f/w3f/NE/biases]
// [B: W1] [C: W2] [D: W3+NE -> vals]. lgkm-only barriers throughout.
// ---------------------------------------------------------------------------
__global__ __launch_bounds__(512, 4) void
scm_main(const float* __restrict__ emb, const float* __restrict__ pab,
         const float* __restrict__ mb1, const float* __restrict__ mb2,
         const float* __restrict__ mb3, const float* __restrict__ adjT,
         const __bf16* __restrict__ wsbf, float* __restrict__ outp) {
    __shared__ unsigned short valsS[32 * 1024];   // [var][b<4][256 d]  64 KB
    __shared__ unsigned short Xs[4 * 264];
    __shared__ unsigned short X2[4 * 264];
    __shared__ unsigned short Hs1[4 * 136];
    __shared__ unsigned short Hs2[4 * 136];

    const int tid = threadIdx.x, blk = blockIdx.x;

    {   // zero vals (ws-independent; harness poisons nothing here -- LDS)
        uint4 z; z.x = z.y = z.z = z.w = 0;
        for (int k = tid; k < 4096; k += 512) ((uint4*)valsS)[k] = z;
    }

    const int wid = tid >> 6, lane = tid & 63, l15 = lane & 15, q = lane >> 4;
    const int l3 = l15 & 3;                 // A-frag row (rows 4..15 aliased, discarded)
    const int nW = wid * 16 + l15;
    const int n0 = nW, n1 = nW + 128;
    const int b = wid & 3, half = wid >> 2;
    const int d2 = half * 128 + lane * 2;   // pc: 2 cols/thread

    const float pb0 = pab[n0], pb1 = pab[n1];
    bar_lds();

    for (int s = 0; s < 3 * N_VARS; s++) {
        const int i = s & 31;
        const bool last = s >= 64;

        // ==== Region P: issue paf; pc compute; issue w1f at end ====
        bf16x8 paf0[8], paf1[8];
        #pragma unroll
        for (int ks = 0; ks < 8; ks++) {
            paf0[ks] = *(const bf16x8*)(wsbf + ELOFF_PA + ((wid * 8 + ks) * 64 + lane) * 8);
            paf1[ks] = *(const bf16x8*)(wsbf + ELOFF_PA + (((wid + 8) * 8 + ks) * 64 + lane) * 8);
        }
        {
            const float* __restrict__ ar = adjT + i * 32;   // wave-uniform s_load
            float2 e2 = *(const float2*)(emb + i * 256 + d2);
            float a0 = 0.f, a1 = 0.f;
            const unsigned short* vp = valsS + b * 256 + d2;
            #pragma unroll
            for (int v = 0; v < 32; v++) {
                unsigned u = *(const unsigned*)(vp + v * 1024);
                float sc = ar[v];
                a0 += sc * __uint_as_float(u << 16);
                a1 += sc * __uint_as_float(u & 0xFFFF0000u);
            }
            *(unsigned*)(Xs + b * 264 + d2) =
                (unsigned)f2b(a0 + e2.x) | ((unsigned)f2b(a1 + e2.y) << 16);
        }
        bf16x8 w1f[8];
        #pragma unroll
        for (int ks = 0; ks < 8; ks++)
            w1f[ks] = *(const bf16x8*)(wsbf + ELOFF_W1 + (size_t)i * 32768 +
                                       ((wid * 8 + ks) * 64 + lane) * 8);
        bar_lds();

        // ==== Region A: pa GEMM; then issue w2f/w3f/NE/biases ====
        {
            f32x4 acc0 = {0, 0, 0, 0}, acc1 = {0, 0, 0, 0};
            #pragma unroll
            for (int ks = 0; ks < 8; ks++) {
                bf16x8 af = *(const bf16x8*)(Xs + l3 * 264 + ks * 32 + q * 8);
                acc0 = MFMA16(af, paf0[ks], acc0);
                acc1 = MFMA16(af, paf1[ks], acc1);
            }
            if (q == 0) {
                #pragma unroll
                for (int r = 0; r < 4; r++) {
                    X2[r * 264 + n0] = f2b(gelu_e(acc0[r] + pb0));
                    X2[r * 264 + n1] = f2b(gelu_e(acc1[r] + pb1));
                }
            }
        }
        bf16x8 w2f[4], w3f0[4], w3f1[4];
        #pragma unroll
        for (int ks = 0; ks < 4; ks++) {
            w2f[ks]  = *(const bf16x8*)(wsbf + ELOFF_W2 + (size_t)i * 16384 +
                                        ((wid * 4 + ks) * 64 + lane) * 8);
            w3f0[ks] = *(const bf16x8*)(wsbf + ELOFF_W3 + (size_t)i * 32768 +
                                        ((wid * 4 + ks) * 64 + lane) * 8);
            w3f1[ks] = *(const bf16x8*)(wsbf + ELOFF_W3 + (size_t)i * 32768 +
                                        (((wid + 8) * 4 + ks) * 64 + lane) * 8);
        }
        float bi1 = mb1[i * 128 + nW];
        float bi2 = mb2[i * 128 + nW];
        float b3a = mb3[i * 256 + n0];
        float b3b = mb3[i * 256 + n1];
        float ne0[4], ne1[4];
        #pragma unroll
        for (int r = 0; r < 4; r++) { ne0[r] = 0.f; ne1[r] = 0.f; }
        if (q == 0) {
            #pragma unroll
            for (int r = 0; r < 4; r++) {
                size_t ob = ((size_t)(blk * BTILE + r) * 32 + i) * 256;
                ne0[r] = outp[ob + n0];
                ne1[r] = outp[ob + n1];
            }
        }
        bar_lds();

        // ==== Region B: W1 GEMM ====
        {
            f32x4 aa = {0, 0, 0, 0}, ab = {0, 0, 0, 0};
            #pragma unroll
            for (int ks = 0; ks < 8; ks += 2) {
                bf16x8 af0 = *(const bf16x8*)(X2 + l3 * 264 + ks * 32 + q * 8);
                bf16x8 af1 = *(const bf16x8*)(X2 + l3 * 264 + (ks + 1) * 32 + q * 8);
                aa = MFMA16(af0, w1f[ks], aa);
                ab = MFMA16(af1, w1f[ks + 1], ab);
            }
            if (q == 0) {
                #pragma unroll
                for (int r = 0; r < 4; r++)
                    Hs1[r * 136 + nW] = f2b(gelu_e(aa[r] + ab[r] + bi1));
            }
        }
        bar_lds();

        // ==== Region C: W2 GEMM ====
        {
            f32x4 acc = {0, 0, 0, 0};
            #pragma unroll
            for (int ks = 0; ks < 4; ks++) {
                bf16x8 af = *(const bf16x8*)(Hs1 + l3 * 136 + ks * 32 + q * 8);
                acc = MFMA16(af, w2f[ks], acc);
            }
            if (q == 0) {
                #pragma unroll
                for (int r = 0; r < 4; r++)
                    Hs2[r * 136 + nW] = f2b(gelu_e(acc[r] + bi2));
            }
        }
        bar_lds();

        // ==== Region D: W3 GEMM + b3 + NE -> vals[i] (and outp at layer 2) ====
        {
            f32x4 acc0 = {0, 0, 0, 0}, acc1 = {0, 0, 0, 0};
            #pragma unroll
            for (int ks = 0; ks < 4; ks++) {
                bf16x8 af = *(const bf16x8*)(Hs2 + l3 * 136 + ks * 32 + q * 8);
                acc0 = MFMA16(af, w3f0[ks], acc0);
                acc1 = MFMA16(af, w3f1[ks], acc1);
            }
            if (q == 0) {
                #pragma unroll
                for (int r = 0; r < 4; r++) {
                    float v0 = acc0[r] + b3a + ne0[r];
                    float v1 = acc1[r] + b3b + ne1[r];
                    valsS[i * 1024 + r * 256 + n0] = f2b(v0);
                    valsS[i * 1024 + r * 256 + n1] = f2b(v1);
                    if (last) {
                        size_t ob = ((size_t)(blk * BTILE + r) * 32 + i) * 256;
                        outp[ob + n0] = v0;
                        outp[ob + n1] = v1;
                    }
                }
            }
        }
        bar_lds();
    }
}

extern "C" void kernel_launch(void* const* d_in, const int* in_sizes, int n_in,
                              void* d_out, int out_size, void* d_ws, size_t ws_size,
                              hipStream_t stream) {
    (void)in_sizes; (void)n_in; (void)out_size; (void)ws_size;
    const float* noise = (const float*)d_in[0];
    const float* edge  = (const float*)d_in[1];
    const float* emb   = (const float*)d_in[2];
    const float* paW   = (const float*)d_in[3];
    const float* pab   = (const float*)d_in[4];
    const float* mW1   = (const float*)d_in[5];
    const float* mb1   = (const float*)d_in[6];
    const float* mW2   = (const float*)d_in[7];
    const float* mb2   = (const float*)d_in[8];
    const float* mW3   = (const float*)d_in[9];
    const float* mb3   = (const float*)d_in[10];
    const float* neW   = (const float*)d_in[11];
    const float* neb   = (const float*)d_in[12];
    float* outp = (float*)d_out;

    float* adjT = (float*)d_ws;
    unsigned short* wsb = (unsigned short*)((char*)d_ws + 4096);

    prep_all<<<1545, 256, 0, stream>>>(paW, mW1, mW2, mW3, edge, wsb, adjT,
                                       noise, neW, neb, outp);
    scm_main<<<NBLK, 512, 0, stream>>>(emb, pab, mb1, mb2, mb3, adjT,
                                       (const __bf16*)wsb, outp);
}

// Round 7
// 489.830 us; speedup vs baseline: 1.6472x; 1.6472x over previous
//
#include <hip/hip_runtime.h>

// ---------------------------------------------------------------------------
// StructuralCausalModel: 3 layers x 32 vars sequential scan, BATCH=512.
// R7: R3's proven spill-free register structure (all step-i fragments loaded
// at step top, plain __launch_bounds__(512) -> compiler picks 128 VGPR, no
// spill) + R6's block-level latency hiding: BTILE=4, 128 blocks, LDS 70.4 KB
// -> 2 blocks/CU co-resident interleave their barrier stalls.
// pc on 4 waves with b64 LDS reads; NE prep fma chain split 4-way.
// ---------------------------------------------------------------------------

typedef __bf16 bf16x8 __attribute__((ext_vector_type(8)));
typedef float  f32x4  __attribute__((ext_vector_type(4)));

#define N_VARS 32
#define BTILE 4
#define NBLK 128

// ws element offsets (bf16 region starts at byte 4096; adjT f32 at byte 0)
#define ELOFF_PA 0
#define ELOFF_W1 65536
#define ELOFF_W2 1114112
#define ELOFF_W3 1638400
// total bf16 el = 2686976 -> ws bytes = 4096 + 5373952

__device__ __forceinline__ unsigned short f2b(float f) {
    unsigned u = __float_as_uint(f);
    u += 0x7FFFu + ((u >> 16) & 1u);
    return (unsigned short)(u >> 16);
}

// lgkm-only barrier: LDS ordering enforced, global loads stay in flight.
__device__ __forceinline__ void bar_lds() {
    asm volatile("s_waitcnt lgkmcnt(0)\n\ts_barrier" ::: "memory");
}

// erf via Abramowitz-Stegun 7.1.25, 3 terms (|err| <= 2.5e-5)
__device__ __forceinline__ float gelu_e(float x) {
    float z  = x * 0.7071067811865476f;
    float az = fabsf(z);
    float t  = __builtin_amdgcn_rcpf(1.0f + 0.47047f * az);
    float p  = t * (0.3480242f + t * (-0.0958798f + t * 0.7478556f));
    float e  = 1.0f - p * __expf(-z * z);
    float er = (z < 0.0f) ? -e : e;
    return 0.5f * x * (1.0f + er);
}

// ---------------------------------------------------------------------------
// Prep (1545 blocks x 256): [0,520) weight swizzle via LDS tile (coalesced);
// 520 adjacency; [521,1545) noise encoder NE -> d_out (16 rows/block).
// B-frag (16x16x32): lane l, elem j -> k = ks*32+(l>>4)*8+j, n = nt*16+(l&15)
// ---------------------------------------------------------------------------
__global__ void prep_all(const float* __restrict__ paW, const float* __restrict__ mW1,
                         const float* __restrict__ mW2, const float* __restrict__ mW3,
                         const float* __restrict__ edge, unsigned short* __restrict__ wsb,
                         float* __restrict__ adjT,
                         const float* __restrict__ noise, const float* __restrict__ neW,
                         const float* __restrict__ neb, float* __restrict__ outp) {
    __shared__ unsigned short tile[32 * 256];
    const int c = blockIdx.x, tid = threadIdx.x;
    if (c < 520) {
        const float* src; unsigned short* dst; int N, KS, ks;
        if (c < 8)        { src = paW;                     dst = wsb + ELOFF_PA;             N = 256; KS = 8; ks = c; }
        else if (c < 264) { int v = (c - 8) >> 3;   ks = (c - 8) & 7;
                            src = mW1 + v * 32768;         dst = wsb + ELOFF_W1 + v * 32768; N = 128; KS = 8; }
        else if (c < 392) { int v = (c - 264) >> 2; ks = (c - 264) & 3;
                            src = mW2 + v * 16384;         dst = wsb + ELOFF_W2 + v * 16384; N = 128; KS = 4; }
        else              { int v = (c - 392) >> 2; ks = (c - 392) & 3;
                            src = mW3 + v * 32768;         dst = wsb + ELOFF_W3 + v * 32768; N = 256; KS = 4; }
        const int kb = ks * 32, nsh = (N == 256) ? 8 : 7;
        for (int t = tid; t < 32 * N; t += 256) {
            int r = t >> nsh, col = t & (N - 1);
            tile[r * N + col] = f2b(src[(kb + r) * N + col]);   // coalesced in col
        }
        __syncthreads();
        const int nout = (N >> 4) * 64;
        for (int o = tid; o < nout; o += 256) {
            int nt = o >> 6, lane = o & 63;
            int n = nt * 16 + (lane & 15), k0 = (lane >> 4) << 3;
            unsigned e[8];
            #pragma unroll
            for (int j = 0; j < 8; j++) e[j] = tile[(k0 + j) * N + n];
            uint4 pk;
            pk.x = e[0] | (e[1] << 16); pk.y = e[2] | (e[3] << 16);
            pk.z = e[4] | (e[5] << 16); pk.w = e[6] | (e[7] << 16);
            *(uint4*)(dst + ((nt * KS + ks) * 64 + lane) * 8) = pk;   // coalesced
        }
    } else if (c == 520) {
        for (int t = tid; t < 1024; t += 256) {
            int v = t >> 5, ci = t & 31;
            float x = edge[t];
            float m = (v == ci) ? 0.0f : x;   // diag logit masked -> adj diag = 0.5
            adjT[ci * 32 + v] = __builtin_amdgcn_rcpf(1.0f + __expf(-2.0f * m));
        }
    } else {
        int sb = c - 521;                     // 1024 sub-blocks: 32 vars x 32 groups
        int i = sb >> 5, g = sb & 31, d = tid;
        float w[64];
        #pragma unroll
        for (int k = 0; k < 64; k++) w[k] = neW[(i * 64 + k) * 256 + d];
        float bias = neb[i * 256 + d];
        for (int bb = 0; bb < 16; bb++) {
            int b = g * 16 + bb;
            const float* nr = noise + (b * 32 + i) * 64;
            float a0 = bias, a1 = 0.f, a2 = 0.f, a3 = 0.f;
            #pragma unroll
            for (int k = 0; k < 16; k++) {      // 4 independent fma chains
                a0 += nr[4 * k + 0] * w[4 * k + 0];
                a1 += nr[4 * k + 1] * w[4 * k + 1];
                a2 += nr[4 * k + 2] * w[4 * k + 2];
                a3 += nr[4 * k + 3] * w[4 * k + 3];
            }
            outp[(b * 32 + i) * 256 + d] = gelu_e((a0 + a1) + (a2 + a3));
        }
    }
}

#define MFMA16(a, b, c) __builtin_amdgcn_mfma_f32_16x16x32_bf16(a, b, c, 0, 0, 0)

// ---------------------------------------------------------------------------
// Main: 128 blocks x 512 threads, 2 blocks/CU (LDS 70.4 KB).
// Per step: [step-top prefetch of ALL globals] pc -> pa -> W1 -> W2 -> W3,
// lgkm-only barriers. Fragments live across the step (R3's 128-reg layout).
// ---------------------------------------------------------------------------
__global__ __launch_bounds__(512) void
scm_main(const float* __restrict__ emb, const float* __restrict__ pab,
         const float* __restrict__ mb1, const float* __restrict__ mb2,
         const float* __restrict__ mb3, const float* __restrict__ adjT,
         const __bf16* __restrict__ wsbf, float* __restrict__ outp) {
    __shared__ unsigned short valsS[32 * 1024];   // [var][b<4][256 d]  64 KB
    __shared__ unsigned short Xs[4 * 264];
    __shared__ unsigned short X2[4 * 264];
    __shared__ unsigned short Hs1[4 * 136];
    __shared__ unsigned short Hs2[4 * 136];

    const int tid = threadIdx.x, blk = blockIdx.x;

    {   // zero vals
        uint4 z; z.x = z.y = z.z = z.w = 0;
        for (int k = tid; k < 4096; k += 512) ((uint4*)valsS)[k] = z;
    }

    const int wid = tid >> 6, lane = tid & 63, l15 = lane & 15, q = lane >> 4;
    const int l3 = l15 & 3;                 // A-frag row (BTILE=4; rows alias)
    const int nW = wid * 16 + l15;
    const int n0 = nW, n1 = nW + 128;
    const int pcb = tid >> 6;               // pc: waves 0..3 -> rows 0..3
    const int d4 = (tid & 63) << 2;         // pc: 4 cols/thread

    const float pb0 = pab[n0], pb1 = pab[n1];
    bar_lds();

    for (int s = 0; s < 3 * N_VARS; s++) {
        const int i = s & 31;
        const bool last = s >= 64;

        // ---- step-top prefetch: ALL globals for this step ----
        const float* __restrict__ ar = adjT + i * 32;      // wave-uniform s_load
        float4 e4;
        if (tid < 256) e4 = *(const float4*)(emb + i * 256 + d4);
        float bi1 = mb1[i * 128 + nW];
        float bi2 = mb2[i * 128 + nW];
        float b3a = mb3[i * 256 + n0];
        float b3b = mb3[i * 256 + n1];
        bf16x8 w1f[8];
        #pragma unroll
        for (int ks = 0; ks < 8; ks++)
            w1f[ks] = *(const bf16x8*)(wsbf + ELOFF_W1 + (size_t)i * 32768 +
                                       ((wid * 8 + ks) * 64 + lane) * 8);
        bf16x8 paf0[8], paf1[8];
        #pragma unroll
        for (int ks = 0; ks < 8; ks++) {
            paf0[ks] = *(const bf16x8*)(wsbf + ELOFF_PA + ((wid * 8 + ks) * 64 + lane) * 8);
            paf1[ks] = *(const bf16x8*)(wsbf + ELOFF_PA + (((wid + 8) * 8 + ks) * 64 + lane) * 8);
        }
        bf16x8 w2f[4], w3f0[4], w3f1[4];
        #pragma unroll
        for (int ks = 0; ks < 4; ks++) {
            w2f[ks]  = *(const bf16x8*)(wsbf + ELOFF_W2 + (size_t)i * 16384 +
                                        ((wid * 4 + ks) * 64 + lane) * 8);
            w3f0[ks] = *(const bf16x8*)(wsbf + ELOFF_W3 + (size_t)i * 32768 +
                                        ((wid * 4 + ks) * 64 + lane) * 8);
            w3f1[ks] = *(const bf16x8*)(wsbf + ELOFF_W3 + (size_t)i * 32768 +
                                        (((wid + 8) * 4 + ks) * 64 + lane) * 8);
        }
        float ne0[4], ne1[4];
        #pragma unroll
        for (int r = 0; r < 4; r++) { ne0[r] = 0.f; ne1[r] = 0.f; }
        if (q == 0) {
            #pragma unroll
            for (int r = 0; r < 4; r++) {
                size_t ob = ((size_t)(blk * BTILE + r) * 32 + i) * 256;
                ne0[r] = outp[ob + n0];
                ne1[r] = outp[ob + n1];
            }
        }

        // ---- pc = sum_v adj[v,i]*vals[b,v,:]; X = bf16(pc + emb_i) ----
        if (tid < 256) {
            float a0 = 0.f, a1 = 0.f, a2 = 0.f, a3 = 0.f;
            const unsigned short* vp = valsS + pcb * 256 + d4;
            #pragma unroll
            for (int v = 0; v < 32; v++) {
                uint2 u = *(const uint2*)(vp + v * 1024);
                float sc = ar[v];
                a0 += sc * __uint_as_float(u.x << 16);
                a1 += sc * __uint_as_float(u.x & 0xFFFF0000u);
                a2 += sc * __uint_as_float(u.y << 16);
                a3 += sc * __uint_as_float(u.y & 0xFFFF0000u);
            }
            uint2 w;
            w.x = (unsigned)f2b(a0 + e4.x) | ((unsigned)f2b(a1 + e4.y) << 16);
            w.y = (unsigned)f2b(a2 + e4.z) | ((unsigned)f2b(a3 + e4.w) << 16);
            *(uint2*)(Xs + pcb * 264 + d4) = w;
        }
        bar_lds();

        // ---- pa: gelu(X @ pa_W + pa_b) ----
        {
            f32x4 acc0 = {0, 0, 0, 0}, acc1 = {0, 0, 0, 0};
            #pragma unroll
            for (int ks = 0; ks < 8; ks++) {
                bf16x8 af = *(const bf16x8*)(Xs + l3 * 264 + ks * 32 + q * 8);
                acc0 = MFMA16(af, paf0[ks], acc0);
                acc1 = MFMA16(af, paf1[ks], acc1);
            }
            if (q == 0) {
                #pragma unroll
                for (int r = 0; r < 4; r++) {
                    X2[r * 264 + n0] = f2b(gelu_e(acc0[r] + pb0));
                    X2[r * 264 + n1] = f2b(gelu_e(acc1[r] + pb1));
                }
            }
        }
        bar_lds();

        // ---- W1: gelu(X2 @ W1 + b1) ----
        {
            f32x4 aa = {0, 0, 0, 0}, ab = {0, 0, 0, 0};
            #pragma unroll
            for (int ks = 0; ks < 8; ks += 2) {
                bf16x8 af0 = *(const bf16x8*)(X2 + l3 * 264 + ks * 32 + q * 8);
                bf16x8 af1 = *(const bf16x8*)(X2 + l3 * 264 + (ks + 1) * 32 + q * 8);
                aa = MFMA16(af0, w1f[ks], aa);
                ab = MFMA16(af1, w1f[ks + 1], ab);
            }
            if (q == 0) {
                #pragma unroll
                for (int r = 0; r < 4; r++)
                    Hs1[r * 136 + nW] = f2b(gelu_e(aa[r] + ab[r] + bi1));
            }
        }
        bar_lds();

        // ---- W2: gelu(h1 @ W2 + b2) ----
        {
            f32x4 acc = {0, 0, 0, 0};
            #pragma unroll
            for (int ks = 0; ks < 4; ks++) {
                bf16x8 af = *(const bf16x8*)(Hs1 + l3 * 136 + ks * 32 + q * 8);
                acc = MFMA16(af, w2f[ks], acc);
            }
            if (q == 0) {
                #pragma unroll
                for (int r = 0; r < 4; r++)
                    Hs2[r * 136 + nW] = f2b(gelu_e(acc[r] + bi2));
            }
        }
        bar_lds();

        // ---- W3: out = h2 @ W3 + b3 + NE; vals[:,i] = out ----
        {
            f32x4 acc0 = {0, 0, 0, 0}, acc1 = {0, 0, 0, 0};
            #pragma unroll
            for (int ks = 0; ks < 4; ks++) {
                bf16x8 af = *(const bf16x8*)(Hs2 + l3 * 136 + ks * 32 + q * 8);
                acc0 = MFMA16(af, w3f0[ks], acc0);
                acc1 = MFMA16(af, w3f1[ks], acc1);
            }
            if (q == 0) {
                #pragma unroll
                for (int r = 0; r < 4; r++) {
                    float v0 = acc0[r] + b3a + ne0[r];
                    float v1 = acc1[r] + b3b + ne1[r];
                    valsS[i * 1024 + r * 256 + n0] = f2b(v0);
                    valsS[i * 1024 + r * 256 + n1] = f2b(v1);
                    if (last) {
                        size_t ob = ((size_t)(blk * BTILE + r) * 32 + i) * 256;
                        outp[ob + n0] = v0;
                        outp[ob + n1] = v1;
                    }
                }
            }
        }
        bar_lds();
    }
}

extern "C" void kernel_launch(void* const* d_in, const int* in_sizes, int n_in,
                              void* d_out, int out_size, void* d_ws, size_t ws_size,
                              hipStream_t stream) {
    (void)in_sizes; (void)n_in; (void)out_size; (void)ws_size;
    const float* noise = (const float*)d_in[0];
    const float* edge  = (const float*)d_in[1];
    const float* emb   = (const float*)d_in[2];
    const float* paW   = (const float*)d_in[3];
    const float* pab   = (const float*)d_in[4];
    const float* mW1   = (const float*)d_in[5];
    const float* mb1   = (const float*)d_in[6];
    const float* mW2   = (const float*)d_in[7];
    const float* mb2   = (const float*)d_in[8];
    const float* mW3   = (const float*)d_in[9];
    const float* mb3   = (const float*)d_in[10];
    const float* neW   = (const float*)d_in[11];
    const float* neb   = (const float*)d_in[12];
    float* outp = (float*)d_out;

    float* adjT = (float*)d_ws;
    unsigned short* wsb = (unsigned short*)((char*)d_ws + 4096);

    prep_all<<<1545, 256, 0, stream>>>(paW, mW1, mW2, mW3, edge, wsb, adjT,
                                       noise, neW, neb, outp);
    scm_main<<<NBLK, 512, 0, stream>>>(emb, pab, mb1, mb2, mb3, adjT,
                                       (const __bf16*)wsb, outp);
}

// Round 8
// 489.141 us; speedup vs baseline: 1.6495x; 1.0014x over previous
//
#include <hip/hip_runtime.h>

// ---------------------------------------------------------------------------
// StructuralCausalModel: 3 layers x 32 vars sequential scan, BATCH=512.
// R8: R7 (BTILE=4, 128 blocks, 2 blocks/CU, step-top prefetch, no spill)
// + R5's delta-pc: the parent aggregate for step i+1 is computed as a full
// 32-term sum during W1/W2 stages (pre-update vals) and corrected after W3
// by a[i,ni]*(new_i - old_i), eliminating the dedicated pc stage from the
// serial chain. ~+6 VGPR over R7's 112 (must stay <=128 / no spill).
// ---------------------------------------------------------------------------

typedef __bf16 bf16x8 __attribute__((ext_vector_type(8)));
typedef float  f32x4  __attribute__((ext_vector_type(4)));

#define N_VARS 32
#define BTILE 4
#define NBLK 128

// ws element offsets (bf16 region starts at byte 4096; adjT f32 at byte 0)
#define ELOFF_PA 0
#define ELOFF_W1 65536
#define ELOFF_W2 1114112
#define ELOFF_W3 1638400
// total bf16 el = 2686976 -> ws bytes = 4096 + 5373952

__device__ __forceinline__ unsigned short f2b(float f) {
    unsigned u = __float_as_uint(f);
    u += 0x7FFFu + ((u >> 16) & 1u);
    return (unsigned short)(u >> 16);
}

// lgkm-only barrier: LDS ordering enforced, global loads stay in flight.
__device__ __forceinline__ void bar_lds() {
    asm volatile("s_waitcnt lgkmcnt(0)\n\ts_barrier" ::: "memory");
}

// erf via Abramowitz-Stegun 7.1.25, 3 terms (|err| <= 2.5e-5)
__device__ __forceinline__ float gelu_e(float x) {
    float z  = x * 0.7071067811865476f;
    float az = fabsf(z);
    float t  = __builtin_amdgcn_rcpf(1.0f + 0.47047f * az);
    float p  = t * (0.3480242f + t * (-0.0958798f + t * 0.7478556f));
    float e  = 1.0f - p * __expf(-z * z);
    float er = (z < 0.0f) ? -e : e;
    return 0.5f * x * (1.0f + er);
}

// ---------------------------------------------------------------------------
// Prep (1545 blocks x 256): [0,520) weight swizzle via LDS tile (coalesced);
// 520 adjacency; [521,1545) noise encoder NE -> d_out (16 rows/block).
// B-frag (16x16x32): lane l, elem j -> k = ks*32+(l>>4)*8+j, n = nt*16+(l&15)
// ---------------------------------------------------------------------------
__global__ void prep_all(const float* __restrict__ paW, const float* __restrict__ mW1,
                         const float* __restrict__ mW2, const float* __restrict__ mW3,
                         const float* __restrict__ edge, unsigned short* __restrict__ wsb,
                         float* __restrict__ adjT,
                         const float* __restrict__ noise, const float* __restrict__ neW,
                         const float* __restrict__ neb, float* __restrict__ outp) {
    __shared__ unsigned short tile[32 * 256];
    const int c = blockIdx.x, tid = threadIdx.x;
    if (c < 520) {
        const float* src; unsigned short* dst; int N, KS, ks;
        if (c < 8)        { src = paW;                     dst = wsb + ELOFF_PA;             N = 256; KS = 8; ks = c; }
        else if (c < 264) { int v = (c - 8) >> 3;   ks = (c - 8) & 7;
                            src = mW1 + v * 32768;         dst = wsb + ELOFF_W1 + v * 32768; N = 128; KS = 8; }
        else if (c < 392) { int v = (c - 264) >> 2; ks = (c - 264) & 3;
                            src = mW2 + v * 16384;         dst = wsb + ELOFF_W2 + v * 16384; N = 128; KS = 4; }
        else              { int v = (c - 392) >> 2; ks = (c - 392) & 3;
                            src = mW3 + v * 32768;         dst = wsb + ELOFF_W3 + v * 32768; N = 256; KS = 4; }
        const int kb = ks * 32, nsh = (N == 256) ? 8 : 7;
        for (int t = tid; t < 32 * N; t += 256) {
            int r = t >> nsh, col = t & (N - 1);
            tile[r * N + col] = f2b(src[(kb + r) * N + col]);   // coalesced in col
        }
        __syncthreads();
        const int nout = (N >> 4) * 64;
        for (int o = tid; o < nout; o += 256) {
            int nt = o >> 6, lane = o & 63;
            int n = nt * 16 + (lane & 15), k0 = (lane >> 4) << 3;
            unsigned e[8];
            #pragma unroll
            for (int j = 0; j < 8; j++) e[j] = tile[(k0 + j) * N + n];
            uint4 pk;
            pk.x = e[0] | (e[1] << 16); pk.y = e[2] | (e[3] << 16);
            pk.z = e[4] | (e[5] << 16); pk.w = e[6] | (e[7] << 16);
            *(uint4*)(dst + ((nt * KS + ks) * 64 + lane) * 8) = pk;   // coalesced
        }
    } else if (c == 520) {
        for (int t = tid; t < 1024; t += 256) {
            int v = t >> 5, ci = t & 31;
            float x = edge[t];
            float m = (v == ci) ? 0.0f : x;   // diag logit masked -> adj diag = 0.5
            adjT[ci * 32 + v] = __builtin_amdgcn_rcpf(1.0f + __expf(-2.0f * m));
        }
    } else {
        int sb = c - 521;                     // 1024 sub-blocks: 32 vars x 32 groups
        int i = sb >> 5, g = sb & 31, d = tid;
        float w[64];
        #pragma unroll
        for (int k = 0; k < 64; k++) w[k] = neW[(i * 64 + k) * 256 + d];
        float bias = neb[i * 256 + d];
        for (int bb = 0; bb < 16; bb++) {
            int b = g * 16 + bb;
            const float* nr = noise + (b * 32 + i) * 64;
            float a0 = bias, a1 = 0.f, a2 = 0.f, a3 = 0.f;
            #pragma unroll
            for (int k = 0; k < 16; k++) {      // 4 independent fma chains
                a0 += nr[4 * k + 0] * w[4 * k + 0];
                a1 += nr[4 * k + 1] * w[4 * k + 1];
                a2 += nr[4 * k + 2] * w[4 * k + 2];
                a3 += nr[4 * k + 3] * w[4 * k + 3];
            }
            outp[(b * 32 + i) * 256 + d] = gelu_e((a0 + a1) + (a2 + a3));
        }
    }
}

#define MFMA16(a, b, c) __builtin_amdgcn_mfma_f32_16x16x32_bf16(a, b, c, 0, 0, 0)

// ---------------------------------------------------------------------------
// Main: 128 blocks x 512 threads, 2 blocks/CU (LDS 70.4 KB).
// Per step: [top prefetch] A:pa  B:W1+pc(v<16)  C:W2+pc(v>=16)  D:W3->vals
// E: pc delta fixup -> Xs(i+1). lgkm-only barriers (5/step).
// ---------------------------------------------------------------------------
__global__ __launch_bounds__(512) void
scm_main(const float* __restrict__ emb, const float* __restrict__ pab,
         const float* __restrict__ mb1, const float* __restrict__ mb2,
         const float* __restrict__ mb3, const float* __restrict__ adjT,
         const __bf16* __restrict__ wsbf, float* __restrict__ outp) {
    __shared__ unsigned short valsS[32 * 1024];   // [var][b<4][256 d]  64 KB
    __shared__ unsigned short Xs[4 * 264];
    __shared__ unsigned short X2[4 * 264];
    __shared__ unsigned short Hs1[4 * 136];
    __shared__ unsigned short Hs2[4 * 136];

    const int tid = threadIdx.x, blk = blockIdx.x;

    {   // zero vals
        uint4 z; z.x = z.y = z.z = z.w = 0;
        for (int k = tid; k < 4096; k += 512) ((uint4*)valsS)[k] = z;
    }

    const int wid = tid >> 6, lane = tid & 63, l15 = lane & 15, q = lane >> 4;
    const int l3 = l15 & 3;                 // A-frag row (BTILE=4; rows alias)
    const int nW = wid * 16 + l15;
    const int n0 = nW, n1 = nW + 128;
    // pc mapping: thread t -> row rE = t>>7, col pair cE = t&127 (cols 2*cE,2*cE+1)
    const int rE = tid >> 7, cE = tid & 127;

    const float pb0 = pab[n0], pb1 = pab[n1];

    // seed Xs for step 0: vals = 0 -> pc = 0 -> X = emb_0
    {
        float2 e0 = *(const float2*)(emb + cE * 2);
        *(unsigned*)(Xs + rE * 264 + cE * 2) =
            (unsigned)f2b(e0.x) | ((unsigned)f2b(e0.y) << 16);
    }
    bar_lds();

    for (int s = 0; s < 3 * N_VARS; s++) {
        const int i = s & 31, ni = (s + 1) & 31;
        const bool last = s >= 64;
        const float* __restrict__ an = adjT + ni * 32;     // wave-uniform s_load

        // ---- step-top prefetch: all step-i globals ----
        float bi1 = mb1[i * 128 + nW];
        float bi2 = mb2[i * 128 + nW];
        float b3a = mb3[i * 256 + n0];
        float b3b = mb3[i * 256 + n1];
        bf16x8 w1f[8];
        #pragma unroll
        for (int ks = 0; ks < 8; ks++)
            w1f[ks] = *(const bf16x8*)(wsbf + ELOFF_W1 + (size_t)i * 32768 +
                                       ((wid * 8 + ks) * 64 + lane) * 8);
        bf16x8 paf0[8], paf1[8];
        #pragma unroll
        for (int ks = 0; ks < 8; ks++) {
            paf0[ks] = *(const bf16x8*)(wsbf + ELOFF_PA + ((wid * 8 + ks) * 64 + lane) * 8);
            paf1[ks] = *(const bf16x8*)(wsbf + ELOFF_PA + (((wid + 8) * 8 + ks) * 64 + lane) * 8);
        }
        bf16x8 w2f[4], w3f0[4], w3f1[4];
        #pragma unroll
        for (int ks = 0; ks < 4; ks++) {
            w2f[ks]  = *(const bf16x8*)(wsbf + ELOFF_W2 + (size_t)i * 16384 +
                                        ((wid * 4 + ks) * 64 + lane) * 8);
            w3f0[ks] = *(const bf16x8*)(wsbf + ELOFF_W3 + (size_t)i * 32768 +
                                        ((wid * 4 + ks) * 64 + lane) * 8);
            w3f1[ks] = *(const bf16x8*)(wsbf + ELOFF_W3 + (size_t)i * 32768 +
                                        (((wid + 8) * 4 + ks) * 64 + lane) * 8);
        }
        float ne0[4], ne1[4];
        #pragma unroll
        for (int r = 0; r < 4; r++) { ne0[r] = 0.f; ne1[r] = 0.f; }
        if (q == 0) {
            #pragma unroll
            for (int r = 0; r < 4; r++) {
                size_t ob = ((size_t)(blk * BTILE + r) * 32 + i) * 256;
                ne0[r] = outp[ob + n0];
                ne1[r] = outp[ob + n1];
            }
        }

        // ==== A: pa = gelu(X @ pa_W + pa_b) ====
        {
            f32x4 acc0 = {0, 0, 0, 0}, acc1 = {0, 0, 0, 0};
            #pragma unroll
            for (int ks = 0; ks < 8; ks++) {
                bf16x8 af = *(const bf16x8*)(Xs + l3 * 264 + ks * 32 + q * 8);
                acc0 = MFMA16(af, paf0[ks], acc0);
                acc1 = MFMA16(af, paf1[ks], acc1);
            }
            if (q == 0) {
                #pragma unroll
                for (int r = 0; r < 4; r++) {
                    X2[r * 264 + n0] = f2b(gelu_e(acc0[r] + pb0));
                    X2[r * 264 + n1] = f2b(gelu_e(acc1[r] + pb1));
                }
            }
        }
        bar_lds();

        // ==== B: W1 GEMM; partial-pc v=0..15 (pre-update vals); old_i snap ====
        float p0 = 0.f, p1 = 0.f, of0, of1;
        {
            f32x4 aa = {0, 0, 0, 0}, ab = {0, 0, 0, 0};
            #pragma unroll
            for (int ks = 0; ks < 8; ks += 2) {
                bf16x8 af0 = *(const bf16x8*)(X2 + l3 * 264 + ks * 32 + q * 8);
                bf16x8 af1 = *(const bf16x8*)(X2 + l3 * 264 + (ks + 1) * 32 + q * 8);
                aa = MFMA16(af0, w1f[ks], aa);
                ab = MFMA16(af1, w1f[ks + 1], ab);
            }
            const unsigned short* vp = valsS + rE * 256 + cE * 2;
            #pragma unroll
            for (int v = 0; v < 16; v++) {
                unsigned u = *(const unsigned*)(vp + v * 1024);
                float sc = an[v];
                p0 += sc * __uint_as_float(u << 16);
                p1 += sc * __uint_as_float(u & 0xFFFF0000u);
            }
            {
                unsigned uo = *(const unsigned*)(valsS + i * 1024 + rE * 256 + cE * 2);
                of0 = __uint_as_float(uo << 16);
                of1 = __uint_as_float(uo & 0xFFFF0000u);
            }
            if (q == 0) {
                #pragma unroll
                for (int r = 0; r < 4; r++)
                    Hs1[r * 136 + nW] = f2b(gelu_e(aa[r] + ab[r] + bi1));
            }
        }
        bar_lds();

        // ==== C: W2 GEMM; partial-pc v=16..31; emb(ni) load ====
        float2 e2n = *(const float2*)(emb + ni * 256 + cE * 2);
        {
            f32x4 acc = {0, 0, 0, 0};
            #pragma unroll
            for (int ks = 0; ks < 4; ks++) {
                bf16x8 af = *(const bf16x8*)(Hs1 + l3 * 136 + ks * 32 + q * 8);
                acc = MFMA16(af, w2f[ks], acc);
            }
            const unsigned short* vp = valsS + rE * 256 + cE * 2;
            #pragma unroll
            for (int v = 16; v < 32; v++) {
                unsigned u = *(const unsigned*)(vp + v * 1024);
                float sc = an[v];
                p0 += sc * __uint_as_float(u << 16);
                p1 += sc * __uint_as_float(u & 0xFFFF0000u);
            }
            if (q == 0) {
                #pragma unroll
                for (int r = 0; r < 4; r++)
                    Hs2[r * 136 + nW] = f2b(gelu_e(acc[r] + bi2));
            }
        }
        bar_lds();

        // ==== D: W3 GEMM + b3 + NE -> vals[i] (and outp at layer 2) ====
        {
            f32x4 acc0 = {0, 0, 0, 0}, acc1 = {0, 0, 0, 0};
            #pragma unroll
            for (int ks = 0; ks < 4; ks++) {
                bf16x8 af = *(const bf16x8*)(Hs2 + l3 * 136 + ks * 32 + q * 8);
                acc0 = MFMA16(af, w3f0[ks], acc0);
                acc1 = MFMA16(af, w3f1[ks], acc1);
            }
            if (q == 0) {
                #pragma unroll
                for (int r = 0; r < 4; r++) {
                    float v0 = acc0[r] + b3a + ne0[r];
                    float v1 = acc1[r] + b3b + ne1[r];
                    valsS[i * 1024 + r * 256 + n0] = f2b(v0);
                    valsS[i * 1024 + r * 256 + n1] = f2b(v1);
                    if (last) {
                        size_t ob = ((size_t)(blk * BTILE + r) * 32 + i) * 256;
                        outp[ob + n0] = v0;
                        outp[ob + n1] = v1;
                    }
                }
            }
        }
        bar_lds();

        // ==== E: pc delta fixup -> Xs for step ni ====
        {
            unsigned un = *(const unsigned*)(valsS + i * 1024 + rE * 256 + cE * 2);
            float av = an[i];                        // a[i, ni]
            float x0 = p0 + av * (__uint_as_float(un << 16)          - of0) + e2n.x;
            float x1 = p1 + av * (__uint_as_float(un & 0xFFFF0000u)  - of1) + e2n.y;
            *(unsigned*)(Xs + rE * 264 + cE * 2) =
                (unsigned)f2b(x0) | ((unsigned)f2b(x1) << 16);
        }
        bar_lds();
    }
}

extern "C" void kernel_launch(void* const* d_in, const int* in_sizes, int n_in,
                              void* d_out, int out_size, void* d_ws, size_t ws_size,
                              hipStream_t stream) {
    (void)in_sizes; (void)n_in; (void)out_size; (void)ws_size;
    const float* noise = (const float*)d_in[0];
    const float* edge  = (const float*)d_in[1];
    const float* emb   = (const float*)d_in[2];
    const float* paW   = (const float*)d_in[3];
    const float* pab   = (const float*)d_in[4];
    const float* mW1   = (const float*)d_in[5];
    const float* mb1   = (const float*)d_in[6];
    const float* mW2   = (const float*)d_in[7];
    const float* mb2   = (const float*)d_in[8];
    const float* mW3   = (const float*)d_in[9];
    const float* mb3   = (const float*)d_in[10];
    const float* neW   = (const float*)d_in[11];
    const float* neb   = (const float*)d_in[12];
    float* outp = (float*)d_out;

    float* adjT = (float*)d_ws;
    unsigned short* wsb = (unsigned short*)((char*)d_ws + 4096);

    prep_all<<<1545, 256, 0, stream>>>(paW, mW1, mW2, mW3, edge, wsb, adjT,
                                       noise, neW, neb, outp);
    scm_main<<<NBLK, 512, 0, stream>>>(emb, pab, mb1, mb2, mb3, adjT,
                                       (const __bf16*)wsb, outp);
}